// Round 2
// baseline (219.453 us; speedup 1.0000x reference)
//
#include <hip/hip_runtime.h>

#define NTOK 65536
#define CCH 64
#define KCB 1024
#define HWSZ 4096
#define CHW 262144           // C*H*W
#define NXQ 4194304          // B*C*H*W
#define NMEAN 4194304.0      // N*C = 65536*64

// ---------------------------------------------------------------------------
// Kernel 1: e2[k] = sum_c E[k][c]^2 ; also zero the loss accumulator in ws.
// ---------------------------------------------------------------------------
__global__ void vq_prep(const float* __restrict__ E,
                        float* __restrict__ e2,
                        double* __restrict__ loss_acc) {
    int k = blockIdx.x * blockDim.x + threadIdx.x;
    if (k == 0) *loss_acc = 0.0;
    if (k < KCB) {
        const float4* e4 = reinterpret_cast<const float4*>(E + k * CCH);
        float s = 0.f;
#pragma unroll
        for (int i = 0; i < 16; ++i) {
            float4 v = e4[i];
            s = fmaf(v.x, v.x, s);
            s = fmaf(v.y, v.y, s);
            s = fmaf(v.z, v.z, s);
            s = fmaf(v.w, v.w, s);
        }
        e2[k] = s;
    }
}

// ---------------------------------------------------------------------------
// Kernel 2: main VQ. 1024 WGs x 256 threads.
//   WG owns 64 consecutive tokens (token-per-lane, channels in VGPRs).
//   Wave w scans codes [w*256, (w+1)*256); code address is wave-uniform
//   (readfirstlane'd wave id) -> compiler emits s_load; code elements feed
//   v_fma_f32 through SGPRs (1 SGPR operand per VALU instr: legal).
//   LDS combine (increasing-k wave order, strict < : first-min semantics),
//   then wave 0 does: indices write, float4 gather of E[best], coalesced
//   per-channel x_q scatter, fused loss, one f64 atomic per WG.
// ---------------------------------------------------------------------------
__global__ __launch_bounds__(256, 4) void vq_main(
    const float* __restrict__ x, const float* __restrict__ E,
    const float* __restrict__ e2, float* __restrict__ out,
    double* __restrict__ loss_acc)
{
    const int lane = threadIdx.x & 63;
    const int wave = __builtin_amdgcn_readfirstlane(threadIdx.x >> 6);
    const int n    = blockIdx.x * 64 + lane;      // token id
    const int b    = n >> 12;                     // n / 4096
    const int hw   = n & 4095;
    const float* xp = x + b * CHW + hw;

    // token channels -> registers (coalesced dword loads across the wave)
    float xr[CCH];
#pragma unroll
    for (int c = 0; c < CCH; ++c) xr[c] = xp[c * HWSZ];

    // scan this wave's 256-code partition
    float best = 3.4e38f;
    int   bidx = 0;
    const int k0 = wave * 256;
    for (int kk = 0; kk < 256; ++kk) {
        const int k = k0 + kk;
        const float4* ek = reinterpret_cast<const float4*>(E + k * CCH);
        float d0 = 0.f, d1 = 0.f, d2 = 0.f, d3 = 0.f;
#pragma unroll
        for (int i = 0; i < 16; ++i) {
            float4 ev = ek[i];                    // wave-uniform -> s_load
            d0 = fmaf(xr[4 * i + 0], ev.x, d0);
            d1 = fmaf(xr[4 * i + 1], ev.y, d1);
            d2 = fmaf(xr[4 * i + 2], ev.z, d2);
            d3 = fmaf(xr[4 * i + 3], ev.w, d3);
        }
        float dot = (d0 + d1) + (d2 + d3);
        float s = fmaf(-2.f, dot, e2[k]);         // ||e||^2 - 2 x.e
        if (s < best) { best = s; bidx = k; }     // strict < : keep lowest k
    }

    // combine the 4 wave-partials per token (wave order = increasing k)
    __shared__ float sb[4][64];
    __shared__ int   si[4][64];
    sb[wave][lane] = best;
    si[wave][lane] = bidx;
    __syncthreads();

    if (wave == 0) {
        float bv = sb[0][lane]; int bi = si[0][lane];
#pragma unroll
        for (int w = 1; w < 4; ++w) {
            float v = sb[w][lane];
            if (v < bv) { bv = v; bi = si[w][lane]; }
        }
        // indices output (flat f32 convention): [B,H,W] after x_q + 2 losses
        out[NXQ + 2 + n] = (float)bi;

        // gather E[bi] via float4 (16 vmem instrs, 4x fewer L1 transactions
        // than 64 scalar gathers), then coalesced per-channel scatter + loss
        const float4* eq = reinterpret_cast<const float4*>(E + bi * CCH);
        float4 qv[16];
#pragma unroll
        for (int i = 0; i < 16; ++i) qv[i] = eq[i];

        float* oq = out + b * CHW + hw;
        float lsum = 0.f;
#pragma unroll
        for (int i = 0; i < 16; ++i) {
            float q0 = qv[i].x, q1 = qv[i].y, q2 = qv[i].z, q3 = qv[i].w;
            oq[(4 * i + 0) * HWSZ] = q0;
            oq[(4 * i + 1) * HWSZ] = q1;
            oq[(4 * i + 2) * HWSZ] = q2;
            oq[(4 * i + 3) * HWSZ] = q3;
            float e0 = q0 - xr[4 * i + 0], e1 = q1 - xr[4 * i + 1];
            float e2d = q2 - xr[4 * i + 2], e3 = q3 - xr[4 * i + 3];
            lsum = fmaf(e0, e0, lsum);
            lsum = fmaf(e1, e1, lsum);
            lsum = fmaf(e2d, e2d, lsum);
            lsum = fmaf(e3, e3, lsum);
        }
        // 64-lane shuffle reduction, one f64 atomic per WG
#pragma unroll
        for (int off = 32; off > 0; off >>= 1)
            lsum += __shfl_xor(lsum, off, 64);
        if (lane == 0) atomicAdd(loss_acc, (double)lsum);
    }
}

// ---------------------------------------------------------------------------
// Kernel 3: finalize both loss scalars (forward values are identical).
// ---------------------------------------------------------------------------
__global__ void vq_final(const double* __restrict__ loss_acc,
                         float* __restrict__ out) {
    if (threadIdx.x == 0) {
        float m = (float)(*loss_acc / NMEAN);
        out[NXQ]     = m;   // codebook_loss
        out[NXQ + 1] = m;   // commitment_loss
    }
}

// ---------------------------------------------------------------------------
extern "C" void kernel_launch(void* const* d_in, const int* in_sizes, int n_in,
                              void* d_out, int out_size, void* d_ws, size_t ws_size,
                              hipStream_t stream) {
    const float* x = (const float*)d_in[0];      // [16,64,64,64] f32
    const float* E = (const float*)d_in[1];      // [1024,64] f32
    float* out = (float*)d_out;                  // [x_q | cb_loss | cm_loss | idx]
    double* loss_acc = (double*)d_ws;            // 8 B
    float*  e2 = (float*)((char*)d_ws + 64);     // 4 KB, 64B-aligned

    vq_prep <<<4,    256, 0, stream>>>(E, e2, loss_acc);
    vq_main <<<1024, 256, 0, stream>>>(x, E, e2, out, loss_acc);
    vq_final<<<1,    64,  0, stream>>>(loss_acc, out);
}

// Round 4
// 176.420 us; speedup vs baseline: 1.2439x; 1.2439x over previous
//
#include <hip/hip_runtime.h>

#define NTOK 65536
#define CCH 64
#define KCB 1024
#define HWSZ 4096
#define CHW 262144           // C*H*W
#define NXQ 4194304          // B*C*H*W
#define NMEAN 4194304.0      // N*C
#define WAVES 8
#define KPW 128              // codes per wave
#define KT 32                // codes per accumulator tile (32 VGPR acc)
#define NTILE 4              // KPW / KT

// ws layout: [0,8) f64 loss | [64, 64+4KB) e2[1024] | [8192, +256KB) ET[64][1024]

// ---------------------------------------------------------------------------
// Kernel 1: e2[k] = ||E[k]||^2 ; ET[c][k] = E[k][c] (transpose); zero loss.
// Thread per code k. ET stores coalesced across lanes (k contiguous).
// ---------------------------------------------------------------------------
__global__ void vq_prep(const float* __restrict__ E,
                        float* __restrict__ e2,
                        float* __restrict__ ET,
                        double* __restrict__ loss_acc) {
    int k = blockIdx.x * blockDim.x + threadIdx.x;
    if (blockIdx.x == 0 && threadIdx.x == 0) *loss_acc = 0.0;
    if (k < KCB) {
        const float4* e4 = reinterpret_cast<const float4*>(E + k * CCH);
        float s = 0.f;
#pragma unroll
        for (int i = 0; i < 16; ++i) {
            float4 v = e4[i];
            ET[(4 * i + 0) * KCB + k] = v.x;
            ET[(4 * i + 1) * KCB + k] = v.y;
            ET[(4 * i + 2) * KCB + k] = v.z;
            ET[(4 * i + 3) * KCB + k] = v.w;
            s = fmaf(v.x, v.x, s);
            s = fmaf(v.y, v.y, s);
            s = fmaf(v.z, v.z, s);
            s = fmaf(v.w, v.w, s);
        }
        e2[k] = s;
    }
}

// ---------------------------------------------------------------------------
// Kernel 2: main VQ. 1024 WGs x 512 threads (8 waves -> 8 waves/SIMD).
//   WG owns 64 consecutive tokens (token-per-lane). Wave w scans codes
//   [w*128, (w+1)*128) as 4 tiles of KT=32 with acc[32] register-resident.
//   Per channel c: one per-lane x load (L1-hot after the xsq pass) + 128 B
//   of ET row via wave-uniform address (s_load, scalar pipe) + 32 indep FMAs.
//   Loss = best + ||x||^2 (== ||x-q||^2), no gather-diff pass needed.
// ---------------------------------------------------------------------------
__global__ __launch_bounds__(512, 8) void vq_main(
    const float* __restrict__ x, const float* __restrict__ E,
    const float* __restrict__ ET, const float* __restrict__ e2,
    float* __restrict__ out, double* __restrict__ loss_acc)
{
    const int lane = threadIdx.x & 63;
    const int wave = __builtin_amdgcn_readfirstlane(threadIdx.x >> 6);
    const int n    = blockIdx.x * 64 + lane;      // token id
    const int b    = n >> 12;
    const int hw   = n & 4095;
    const float* xp = x + b * CHW + hw;

    // ||x||^2 pass (also warms L1 with this block's x-tile)
    float xsq = 0.f;
#pragma unroll 8
    for (int c = 0; c < CCH; ++c) {
        float xv = xp[c * HWSZ];
        xsq = fmaf(xv, xv, xsq);
    }

    float best = 3.4e38f;
    int   bidx = 0;
    const int k0w = wave * KPW;

#pragma unroll 1
    for (int t = 0; t < NTILE; ++t) {
        const int k0 = k0w + t * KT;
        float acc[KT];
#pragma unroll
        for (int j = 0; j < KT; ++j) acc[j] = 0.f;

        const float* etb = ET + k0;
#pragma unroll 2
        for (int c = 0; c < CCH; ++c) {
            float xv = xp[c * HWSZ];              // per-lane vmem, L1-hot
            const float4* er = reinterpret_cast<const float4*>(etb + c * KCB);
#pragma unroll
            for (int j4 = 0; j4 < KT / 4; ++j4) {
                float4 ev = er[j4];               // wave-uniform -> s_load
                acc[4 * j4 + 0] = fmaf(xv, ev.x, acc[4 * j4 + 0]);
                acc[4 * j4 + 1] = fmaf(xv, ev.y, acc[4 * j4 + 1]);
                acc[4 * j4 + 2] = fmaf(xv, ev.z, acc[4 * j4 + 2]);
                acc[4 * j4 + 3] = fmaf(xv, ev.w, acc[4 * j4 + 3]);
            }
        }
        // finalize tile: s = ||e||^2 - 2 x.e ; strict < keeps lowest k
#pragma unroll
        for (int j = 0; j < KT; ++j) {
            float s = fmaf(-2.f, acc[j], e2[k0 + j]);
            if (s < best) { best = s; bidx = k0 + j; }
        }
    }

    // combine 8 wave-partials per token (wave order = increasing k)
    __shared__ float sb[WAVES][64];
    __shared__ int   si[WAVES][64];
    sb[wave][lane] = best;
    si[wave][lane] = bidx;
    __syncthreads();

    if (wave == 0) {
        float bv = sb[0][lane]; int bi = si[0][lane];
#pragma unroll
        for (int w = 1; w < WAVES; ++w) {
            float v = sb[w][lane];
            if (v < bv) { bv = v; bi = si[w][lane]; }
        }
        // indices output (flat f32): after x_q + 2 loss scalars
        out[NXQ + 2 + n] = (float)bi;

        // fused loss: ||x - e_bi||^2 = (||e||^2 - 2 x.e) + ||x||^2
        float lsum = bv + xsq;
#pragma unroll
        for (int off = 32; off > 0; off >>= 1)
            lsum += __shfl_xor(lsum, off, 64);
        if (lane == 0) atomicAdd(loss_acc, (double)lsum);

        // x_q = E[bi] scattered to [B,C,H,W]; chunked to cap VGPR use
        const float4* eq = reinterpret_cast<const float4*>(E + bi * CCH);
        float* oq = out + b * CHW + hw;
#pragma unroll 1
        for (int g = 0; g < 4; ++g) {
            float4 q0 = eq[4 * g + 0];
            float4 q1 = eq[4 * g + 1];
            float4 q2 = eq[4 * g + 2];
            float4 q3 = eq[4 * g + 3];
            float* o = oq + (16 * g) * HWSZ;
            o[0 * HWSZ] = q0.x; o[1 * HWSZ] = q0.y; o[2 * HWSZ] = q0.z; o[3 * HWSZ] = q0.w;
            o[4 * HWSZ] = q1.x; o[5 * HWSZ] = q1.y; o[6 * HWSZ] = q1.z; o[7 * HWSZ] = q1.w;
            o[8 * HWSZ] = q2.x; o[9 * HWSZ] = q2.y; o[10 * HWSZ] = q2.z; o[11 * HWSZ] = q2.w;
            o[12 * HWSZ] = q3.x; o[13 * HWSZ] = q3.y; o[14 * HWSZ] = q3.z; o[15 * HWSZ] = q3.w;
        }
    }
}

// ---------------------------------------------------------------------------
// Kernel 3: finalize both loss scalars (forward values identical).
// ---------------------------------------------------------------------------
__global__ void vq_final(const double* __restrict__ loss_acc,
                         float* __restrict__ out) {
    if (threadIdx.x == 0) {
        float m = (float)(*loss_acc / NMEAN);
        out[NXQ]     = m;   // codebook_loss
        out[NXQ + 1] = m;   // commitment_loss
    }
}

// ---------------------------------------------------------------------------
extern "C" void kernel_launch(void* const* d_in, const int* in_sizes, int n_in,
                              void* d_out, int out_size, void* d_ws, size_t ws_size,
                              hipStream_t stream) {
    const float* x = (const float*)d_in[0];      // [16,64,64,64] f32
    const float* E = (const float*)d_in[1];      // [1024,64] f32
    float* out = (float*)d_out;                  // [x_q | cb_loss | cm_loss | idx]
    double* loss_acc = (double*)d_ws;            // 8 B
    float*  e2 = (float*)((char*)d_ws + 64);     // 4 KB
    float*  ET = (float*)((char*)d_ws + 8192);   // 256 KB transpose

    vq_prep <<<4,    256, 0, stream>>>(E, e2, ET, loss_acc);
    vq_main <<<1024, 512, 0, stream>>>(x, E, ET, e2, out, loss_acc);
    vq_final<<<1,    64,  0, stream>>>(loss_acc, out);
}

// Round 6
// 145.892 us; speedup vs baseline: 1.5042x; 1.2093x over previous
//
#include <hip/hip_runtime.h>

typedef short s16x8 __attribute__((ext_vector_type(8)));   // 8 bf16 (4 VGPR) MFMA frag
typedef float f32x4 __attribute__((ext_vector_type(4)));   // MFMA C/D frag

#define NTOK 65536
#define CCH 64
#define KCB 1024
#define HWSZ 4096
#define CHW 262144            // C*H*W
#define NXQ 4194304           // B*C*H*W
#define NMEAN 4194304.0       // N*C
#define PLANE_BYTES 131072    // 1024 codes * 64 ch * 2B

static __device__ __forceinline__ unsigned short f2bf(float f) {
    unsigned int u = __float_as_uint(f);
    return (unsigned short)((u + 0x7FFFu + ((u >> 16) & 1u)) >> 16);  // RNE
}
static __device__ __forceinline__ float bf2f(unsigned short b) {
    return __uint_as_float(((unsigned int)b) << 16);
}

// ---------------------------------------------------------------------------
// Kernel 1 (8192 thr): pack -2*E into 3 bf16 split planes in MFMA-B frag
// order; e2[k] = ||E[k]||^2 (f32 exact); zero loss accumulator.
// Plane entry gid = nt*128 + ks*64 + l holds code col=(l&15) of N-tile nt,
// channels c = ks*32 + (l>>4)*8 + j  (same (g,j)->c map as the A frags, so
// the in-fragment k-permutation cancels in the MFMA dot).
// ---------------------------------------------------------------------------
__global__ void vq_prep(const float* __restrict__ E, float* __restrict__ e2,
                        s16x8* __restrict__ Bh, s16x8* __restrict__ Bm,
                        s16x8* __restrict__ Bl, double* __restrict__ loss_acc) {
    int gid = blockIdx.x * blockDim.x + threadIdx.x;   // 0..8191
    if (gid == 0) *loss_acc = 0.0;
    {
        int nt = gid >> 7, rem = gid & 127;
        int ks = rem >> 6, l = rem & 63;
        int code = nt * 16 + (l & 15);
        int cb   = ks * 32 + ((l >> 4) << 3);
        const float* ep = E + code * CCH + cb;
        s16x8 vh, vm, vl;
#pragma unroll
        for (int j = 0; j < 8; ++j) {
            float v = -2.f * ep[j];                    // exact scaling
            unsigned short h  = f2bf(v);  float r1 = v  - bf2f(h);
            unsigned short md = f2bf(r1); float r2 = r1 - bf2f(md);
            unsigned short lo = f2bf(r2);
            vh[j] = (short)h; vm[j] = (short)md; vl[j] = (short)lo;
        }
        Bh[gid] = vh; Bm[gid] = vm; Bl[gid] = vl;
    }
    if (gid < KCB) {
        const float4* e4 = reinterpret_cast<const float4*>(E + gid * CCH);
        float s = 0.f;
#pragma unroll
        for (int i = 0; i < 16; ++i) {
            float4 v = e4[i];
            s = fmaf(v.x, v.x, s); s = fmaf(v.y, v.y, s);
            s = fmaf(v.z, v.z, s); s = fmaf(v.w, v.w, s);
        }
        e2[gid] = s;
    }
}

// ---------------------------------------------------------------------------
// Kernel 2: MFMA VQ. 1024 WGs x 512 thr (8 waves). WG owns 64 tokens.
//   Prologue: stage x -> 3 bf16 LDS planes [tok][ch], XOR-swizzled
//   (byte ^= (tok&7)<<4); then each wave hoists ALL its A-frags (4 M-tiles
//   x 2 ksteps x 3 planes = 96 VGPR) to registers ONCE — LDS traffic 4x
//   lower than re-reading per chunk (round-4 post-hoc analysis).
//   Wave w scans codes [w*128,(w+1)*128) in 4 chunks of 32: acc seeded
//   with e2[k]; 6 split-MFMAs (hh,hm,mh,mm,hl,lh) give s = e2 - 2 x.e at
//   ~f32 precision. Per-lane argmin (strict <, k ascending), 16-lane shfl
//   reduce (tie -> lower k), 8-wave LDS combine (ascending k).
// ---------------------------------------------------------------------------
__global__ __launch_bounds__(512, 2) void vq_main(
    const float* __restrict__ x, const float* __restrict__ E,
    const s16x8* __restrict__ Bh, const s16x8* __restrict__ Bm,
    const s16x8* __restrict__ Bl, const float* __restrict__ e2,
    float* __restrict__ out, double* __restrict__ loss_acc)
{
    __shared__ __align__(16) short XH[64 * 64];
    __shared__ __align__(16) short XM[64 * 64];
    __shared__ __align__(16) short XL[64 * 64];
    __shared__ float XSQ[8][64];
    __shared__ float SB[8][64];
    __shared__ int   SI[8][64];

    const int t    = threadIdx.x;
    const int lane = t & 63;
    const int w    = t >> 6;
    const int n0   = blockIdx.x * 64;
    const int b    = n0 >> 12;                 // constant per block (64|4096)
    const int hw0  = n0 & 4095;

    // ---- stage x: thread handles channels cb*8..cb*8+7 of token tok ----
    {
        const int tok = t & 63;
        const int cb  = t >> 6;                // 0..7
        const float* xp = x + b * CHW + hw0 + tok;
        float xs = 0.f;
        s16x8 ph, pm, pl;
#pragma unroll
        for (int j = 0; j < 8; ++j) {
            float v = xp[(cb * 8 + j) * HWSZ];         // coalesced per j
            xs = fmaf(v, v, xs);
            unsigned short h  = f2bf(v);  float r1 = v  - bf2f(h);
            unsigned short md = f2bf(r1); float r2 = r1 - bf2f(md);
            unsigned short lo = f2bf(r2);
            ph[j] = (short)h; pm[j] = (short)md; pl[j] = (short)lo;
        }
        XSQ[cb][tok] = xs;
        const int wofs = tok * 128 + ((cb * 16) ^ ((tok & 7) << 4));
        *reinterpret_cast<s16x8*>((char*)XH + wofs) = ph;
        *reinterpret_cast<s16x8*>((char*)XM + wofs) = pm;
        *reinterpret_cast<s16x8*>((char*)XL + wofs) = pl;
    }
    __syncthreads();

    const int g   = lane >> 4;
    const int c15 = lane & 15;

    // ---- hoist A-frags: [m][ks], 24 x s16x8, read LDS exactly once ----
    s16x8 ah[4][2], am[4][2], al[4][2];
#pragma unroll
    for (int m = 0; m < 4; ++m) {
        const int row = m * 16 + c15;
        const int rb  = row * 128;
        const int swz = (row & 7) << 4;
#pragma unroll
        for (int ks = 0; ks < 2; ++ks) {
            int off = rb + ((ks * 64 + g * 16) ^ swz);
            ah[m][ks] = *reinterpret_cast<const s16x8*>((const char*)XH + off);
            am[m][ks] = *reinterpret_cast<const s16x8*>((const char*)XM + off);
            al[m][ks] = *reinterpret_cast<const s16x8*>((const char*)XL + off);
        }
    }

    float e2w[8];
#pragma unroll
    for (int i = 0; i < 8; ++i) e2w[i] = e2[w * 128 + i * 16 + c15];

    float best[4][4];
    int   bidx[4][4];
#pragma unroll
    for (int m = 0; m < 4; ++m)
#pragma unroll
        for (int r = 0; r < 4; ++r) { best[m][r] = 3.4e38f; bidx[m][r] = 0; }

#pragma unroll 1
    for (int ch = 0; ch < 4; ++ch) {
        s16x8 bh[2][2], bm[2][2], bl[2][2];          // [nt][ks]
#pragma unroll
        for (int nt = 0; nt < 2; ++nt)
#pragma unroll
            for (int ks = 0; ks < 2; ++ks) {
                int idx = ((w * 8 + ch * 2 + nt) * 2 + ks) * 64 + lane;
                bh[nt][ks] = Bh[idx];
                bm[nt][ks] = Bm[idx];
                bl[nt][ks] = Bl[idx];
            }

        f32x4 acc[4][2];
#pragma unroll
        for (int m = 0; m < 4; ++m)
#pragma unroll
            for (int nt = 0; nt < 2; ++nt) {
                float s0 = e2w[ch * 2 + nt];          // seed: ||e||^2
                acc[m][nt] = (f32x4){s0, s0, s0, s0};
            }

#pragma unroll
        for (int m = 0; m < 4; ++m)
#pragma unroll
            for (int nt = 0; nt < 2; ++nt)
#pragma unroll
                for (int ks = 0; ks < 2; ++ks) {
                    acc[m][nt] = __builtin_amdgcn_mfma_f32_16x16x32_bf16(ah[m][ks], bh[nt][ks], acc[m][nt], 0, 0, 0);
                    acc[m][nt] = __builtin_amdgcn_mfma_f32_16x16x32_bf16(ah[m][ks], bm[nt][ks], acc[m][nt], 0, 0, 0);
                    acc[m][nt] = __builtin_amdgcn_mfma_f32_16x16x32_bf16(am[m][ks], bh[nt][ks], acc[m][nt], 0, 0, 0);
                    acc[m][nt] = __builtin_amdgcn_mfma_f32_16x16x32_bf16(am[m][ks], bm[nt][ks], acc[m][nt], 0, 0, 0);
                    acc[m][nt] = __builtin_amdgcn_mfma_f32_16x16x32_bf16(ah[m][ks], bl[nt][ks], acc[m][nt], 0, 0, 0);
                    acc[m][nt] = __builtin_amdgcn_mfma_f32_16x16x32_bf16(al[m][ks], bh[nt][ks], acc[m][nt], 0, 0, 0);
                }

        // argmin update: nt ascending => k ascending; strict < keeps first
#pragma unroll
        for (int nt = 0; nt < 2; ++nt) {
            const int k = w * 128 + ch * 32 + nt * 16 + c15;
#pragma unroll
            for (int m = 0; m < 4; ++m)
#pragma unroll
                for (int r = 0; r < 4; ++r) {
                    float s = acc[m][nt][r];
                    if (s < best[m][r]) { best[m][r] = s; bidx[m][r] = k; }
                }
        }
    }

    // ---- cross-lane reduce over the 16 cols (same token rows) ----
#pragma unroll
    for (int m = 0; m < 4; ++m)
#pragma unroll
        for (int r = 0; r < 4; ++r) {
            float v = best[m][r]; int k = bidx[m][r];
#pragma unroll
            for (int off = 1; off < 16; off <<= 1) {
                float ov = __shfl_xor(v, off, 64);
                int   ok = __shfl_xor(k, off, 64);
                if (ov < v || (ov == v && ok < k)) { v = ov; k = ok; }
            }
            if (c15 == 0) {
                int tk = m * 16 + g * 4 + r;       // C/D row (m89-verified)
                SB[w][tk] = v; SI[w][tk] = k;
            }
        }
    __syncthreads();

    // ---- wave 0: combine 8 waves (asc wave = asc k), outputs ----
    if (w == 0) {
        float bv = SB[0][lane]; int bi = SI[0][lane];
#pragma unroll
        for (int ww = 1; ww < 8; ++ww) {
            float v = SB[ww][lane];
            if (v < bv) { bv = v; bi = SI[ww][lane]; }
        }
        out[NXQ + 2 + n0 + lane] = (float)bi;

        float xsq = 0.f;
#pragma unroll
        for (int c = 0; c < 8; ++c) xsq += XSQ[c][lane];
        float lsum = bv + xsq;                     // ||x-q||^2
#pragma unroll
        for (int off = 32; off > 0; off >>= 1)
            lsum += __shfl_xor(lsum, off, 64);
        if (lane == 0) atomicAdd(loss_acc, (double)lsum);

        // x_q = E[bi] (exact f32 copy), coalesced per-channel scatter
        const float4* eq = reinterpret_cast<const float4*>(E + bi * CCH);
        float* oq = out + b * CHW + hw0 + lane;
#pragma unroll 1
        for (int gq = 0; gq < 4; ++gq) {
            float4 q0 = eq[4 * gq + 0];
            float4 q1 = eq[4 * gq + 1];
            float4 q2 = eq[4 * gq + 2];
            float4 q3 = eq[4 * gq + 3];
            float* o = oq + (16 * gq) * HWSZ;
            o[0 * HWSZ] = q0.x; o[1 * HWSZ]  = q0.y; o[2 * HWSZ]  = q0.z; o[3 * HWSZ]  = q0.w;
            o[4 * HWSZ] = q1.x; o[5 * HWSZ]  = q1.y; o[6 * HWSZ]  = q1.z; o[7 * HWSZ]  = q1.w;
            o[8 * HWSZ] = q2.x; o[9 * HWSZ]  = q2.y; o[10 * HWSZ] = q2.z; o[11 * HWSZ] = q2.w;
            o[12 * HWSZ] = q3.x; o[13 * HWSZ] = q3.y; o[14 * HWSZ] = q3.z; o[15 * HWSZ] = q3.w;
        }
    }
}

// ---------------------------------------------------------------------------
// Kernel 3: finalize both loss scalars (forward values identical).
// ---------------------------------------------------------------------------
__global__ void vq_final(const double* __restrict__ loss_acc,
                         float* __restrict__ out) {
    if (threadIdx.x == 0) {
        float m = (float)(*loss_acc / NMEAN);
        out[NXQ]     = m;
        out[NXQ + 1] = m;
    }
}

// ---------------------------------------------------------------------------
extern "C" void kernel_launch(void* const* d_in, const int* in_sizes, int n_in,
                              void* d_out, int out_size, void* d_ws, size_t ws_size,
                              hipStream_t stream) {
    const float* x = (const float*)d_in[0];          // [16,64,64,64] f32
    const float* E = (const float*)d_in[1];          // [1024,64] f32
    float* out = (float*)d_out;                      // [x_q | cb | cm | idx]
    double* loss_acc = (double*)d_ws;                // 8 B
    float*  e2 = (float*)((char*)d_ws + 64);         // 4 KB
    s16x8*  Bh = (s16x8*)((char*)d_ws + 8192);
    s16x8*  Bm = (s16x8*)((char*)d_ws + 8192 + PLANE_BYTES);
    s16x8*  Bl = (s16x8*)((char*)d_ws + 8192 + 2 * PLANE_BYTES);

    vq_prep <<<32,   256, 0, stream>>>(E, e2, Bh, Bm, Bl, loss_acc);
    vq_main <<<1024, 512, 0, stream>>>(x, E, Bh, Bm, Bl, e2, out, loss_acc);
    vq_final<<<1,    64,  0, stream>>>(loss_acc, out);
}